// Round 1
// baseline (166.489 us; speedup 1.0000x reference)
//
#include <hip/hip_runtime.h>

// LowRankSig_HigherOrder: B=32, T=2048, F=64 (time + 63), K=10 tensors, U=64 units.
// Strategy: affine-scan decomposition. T split into 128 sub-chunks of 16 rows.
// Each wave computes its chunk's M tile (fp32 dot products, lane = u), scans it
// locally with zero initial state, and writes 17 scalars per (b,u,chunk):
//   q0  o    : local out contribution
//   q1  a1   : d(out)/d(c1_in)      q2  a3 : d(out)/d(c3_in)
//   q3  aA   : d(out)/d(cA_in)      q4  a6 : d(out)/d(c6_in)
//   q5  aP   : d(out)/d(cP_in)      q6  aQ : d(out)/d(cQ_in)
//   q7  d1, q8 d3, q9 dA, q10 d6, q11 dP, q12 dQ : state increments (zero-init)
//   q13 tA3 (cA<-c3), q14 tP6 (cP<-c6), q15 tQP (cQ<-cP), q16 tQ6 (cQ<-c6)
// A second tiny kernel composes the 128 affine maps sequentially per (b,u).

#define TT 2048
#define NFX 63
#define KT 10
#define NU 64
#define LDSW 68      // padded row stride for XaT [f][row]
#define NQ 17
#define NCC 128      // sub-chunks (16 rows each) per batch
#define WGC 32       // workgroup chunks (64 rows each) per batch

template<int KP>
__device__ __forceinline__ void compute_m(
    const float* __restrict__ Kw, const float* __restrict__ XaT,
    int w, int u, int kbase, float (&acc)[17][KP])
{
#pragma unroll
  for (int r = 0; r < 17; ++r)
#pragma unroll
    for (int k = 0; k < KP; ++k) acc[r][k] = 0.f;

  const int rowbase = 16 * w;
  for (int f = 0; f < 64; ++f) {
    const float* xb = &XaT[f * LDSW + rowbase];
    float xr[17];
#pragma unroll
    for (int r4 = 0; r4 < 4; ++r4) {
      float4 v = *reinterpret_cast<const float4*>(xb + 4 * r4);
      xr[4*r4+0] = v.x; xr[4*r4+1] = v.y; xr[4*r4+2] = v.z; xr[4*r4+3] = v.w;
    }
    xr[16] = xb[16];
    const float* kp = &Kw[f * (KT*NU) + kbase * NU + u];
#pragma unroll
    for (int k = 0; k < KP; ++k) {
      float kv = kp[k * NU];
#pragma unroll
      for (int r = 0; r < 17; ++r)
        acc[r][k] = fmaf(xr[r], kv, acc[r][k]);
    }
  }
}

__global__ __launch_bounds__(256)
void lrsig_chunk_kernel(const float* __restrict__ X,
                        const float* __restrict__ Kw,
                        float* __restrict__ ws)
{
  __shared__ float XaT[64 * LDSW];   // transposed Xa tile: [f][row], 65 rows used

  const int b = blockIdx.y;
  const int c = blockIdx.x;          // 0..31, 64 rows per WG
  const int tid = threadIdx.x;
  const int u = tid & 63;
  const int w = tid >> 6;            // wave id 0..3, handles rows [16w,16w+16)
  const int t0 = c * 64;             // global start row of WG chunk

  // ---- load Xa tile (rows t0-1 .. t0+63), transposed into LDS ----
  for (int idx = tid; idx < 65 * NFX; idx += 256) {
    int row = idx / NFX;
    int col = idx - row * NFX;
    int gt = t0 - 1 + row; if (gt < 0) gt = 0;   // duplicate row 0 -> diff 0 at t=0
    XaT[(col + 1) * LDSW + row] = X[((size_t)b * TT + gt) * NFX + col];
  }
  for (int idx = tid; idx < 65; idx += 256) {
    int gt = t0 - 1 + idx; if (gt < 0) gt = 0;
    XaT[idx] = (float)gt * (2.0f / 2047.0f) - 1.0f;   // time feature f=0
  }
  __syncthreads();

  float outq[NQ];

  // ---------- phase A: k = 0,1,2  (level-0 + m=1 chain) ----------
  {
    float acc[17][3];
    compute_m<3>(Kw, XaT, w, u, 0, acc);
    float oA = 0.f, a1 = 0.f, lc1 = 0.f;
#pragma unroll
    for (int t = 0; t < 16; ++t) {
      float m0 = acc[t+1][0] - acc[t][0];
      float m1 = acc[t+1][1] - acc[t][1];
      float m2 = acc[t+1][2] - acc[t][2];
      oA += m0 + m2 * (lc1 + 0.5f * m1);
      a1 += m2;
      lc1 += m1;
    }
    outq[0] = oA; outq[1] = a1; outq[7] = lc1;
  }

  // ---------- phase B: k = 3,4,5  (m=2 chain) ----------
  {
    float acc[17][3];
    compute_m<3>(Kw, XaT, w, u, 3, acc);
    float oB = 0.f, a3 = 0.f, aA = 0.f;
    float lc3 = 0.f, lcA = 0.f, g4 = 0.f;
#pragma unroll
    for (int t = 0; t < 16; ++t) {
      float m3 = acc[t+1][0] - acc[t][0];
      float m4 = acc[t+1][1] - acc[t][1];
      float m5 = acc[t+1][2] - acc[t][2];
      float s0 = m4 * lc3;
      float s1 = 0.5f * m4 * m3;
      oB += m5 * (lcA + 0.5f * s0 + (1.f/3.f) * s1);
      a3 += m5 * (g4 + 0.5f * m4);
      aA += m5;
      lcA += s0 + s1;
      g4  += m4;
      lc3 += m3;
    }
    outq[0] += oB;
    outq[2] = a3; outq[3] = aA; outq[8] = lc3; outq[9] = lcA; outq[13] = g4;
  }

  // ---------- phase C: k = 6,7,8,9  (m=3 chain) ----------
  {
    float acc[17][4];
    compute_m<4>(Kw, XaT, w, u, 6, acc);
    float oC = 0.f, a6 = 0.f, aP = 0.f, aQ = 0.f;
    float lc6 = 0.f, lcP = 0.f, lcQ = 0.f, g7 = 0.f, g8 = 0.f, h = 0.f;
#pragma unroll
    for (int t = 0; t < 16; ++t) {
      float m6 = acc[t+1][0] - acc[t][0];
      float m7 = acc[t+1][1] - acc[t][1];
      float m8 = acc[t+1][2] - acc[t][2];
      float m9 = acc[t+1][3] - acc[t][3];
      float p0 = m7 * lc6;
      float p1 = 0.5f * m7 * m6;
      float q0 = m8 * lcP;
      float q1 = 0.5f * m8 * p0;
      float q2 = (1.f/3.f) * m8 * p1;
      oC += m9 * (lcQ + 0.5f * q0 + (1.f/3.f) * q1 + 0.25f * q2);
      a6 += m9 * (h + m8 * (0.5f * g7 + (1.f/6.f) * m7));
      aP += m9 * (g8 + 0.5f * m8);
      aQ += m9;
      h  += m8 * (g7 + 0.5f * m7);   // uses exclusive g7, before g7 update
      lcP += p0 + p1;
      lcQ += q0 + q1 + q2;
      g7 += m7; g8 += m8; lc6 += m6;
    }
    outq[0] += oC;
    outq[4] = a6; outq[5] = aP; outq[6] = aQ;
    outq[10] = lc6; outq[11] = lcP; outq[12] = lcQ;
    outq[14] = g7; outq[15] = g8; outq[16] = h;
  }

  // ---- write 17 scalars, coalesced over u ----
  const int cc = c * 4 + w;          // global sub-chunk index, time-ordered
  float* p = &ws[(((size_t)b * NCC + cc) * NQ) * NU + u];
#pragma unroll
  for (int q = 0; q < NQ; ++q) p[q * NU] = outq[q];
}

__global__ __launch_bounds__(256)
void lrsig_combine_kernel(const float* __restrict__ ws, float* __restrict__ out)
{
  const int gid = blockIdx.x * blockDim.x + threadIdx.x;   // 0..2047
  const int u = gid & 63;
  const int b = gid >> 6;
  float c1 = 0.f, c3 = 0.f, cA = 0.f, c6 = 0.f, cP = 0.f, cQ = 0.f, o = 0.f;
  for (int cc = 0; cc < NCC; ++cc) {
    const float* p = &ws[(((size_t)b * NCC + cc) * NQ) * NU + u];
    float q[NQ];
#pragma unroll
    for (int i = 0; i < NQ; ++i) q[i] = p[i * NU];
    o  += q[0] + q[1]*c1 + q[2]*c3 + q[3]*cA + q[4]*c6 + q[5]*cP + q[6]*cQ;
    cA += q[13]*c3 + q[9];           // uses c3_in
    cQ += q[15]*cP + q[16]*c6 + q[12]; // uses cP_in, c6_in
    cP += q[14]*c6 + q[11];          // uses c6_in
    c1 += q[7]; c3 += q[8]; c6 += q[10];
  }
  out[gid] = o;
}

extern "C" void kernel_launch(void* const* d_in, const int* in_sizes, int n_in,
                              void* d_out, int out_size, void* d_ws, size_t ws_size,
                              hipStream_t stream) {
  const float* X  = (const float*)d_in[0];   // (32, 2048, 63) fp32
  const float* Kw = (const float*)d_in[1];   // (64, 10, 64)   fp32
  float* out = (float*)d_out;                // (32, 64)       fp32
  float* ws  = (float*)d_ws;                 // needs 32*128*17*64*4 = 17.8 MB

  hipLaunchKernelGGL(lrsig_chunk_kernel, dim3(WGC, 32), dim3(256), 0, stream,
                     X, Kw, ws);
  hipLaunchKernelGGL(lrsig_combine_kernel, dim3(8), dim3(256), 0, stream,
                     ws, out);
}